// Round 7
// baseline (2435.784 us; speedup 1.0000x reference)
//
#include <hip/hip_runtime.h>
#include <math.h>

#define NX 8192
#define NY 65536
#define DIM 512
#define KNN 8

#define BM 128                 // Y rows per tile (MFMA M side)
#define BN 128                 // X rows per block (MFMA N side)
#define BK 64                  // K step
#define NCH 16                 // Y chunks per pass (grid.x) -> 4 blocks/CU
#define NPASS 2                // sequential Y passes (2 chunks/XCD -> 4 MB, L2-fits)
#define ROWS_PER_PASS (NY / NPASS)            // 32768
#define COLS_PER_CHUNK (ROWS_PER_PASS / NCH)  // 2048 Y rows per chunk
#define TILES_PER_CHUNK (COLS_PER_CHUNK / BM) // 16
#define LPT 8                  // per-lane top-K per X-row (packed keys)
#define KEEP 8                 // kept per (row, chunk)
#define NCAND (NPASS * NCH * KEEP)   // 256 candidates per row (unchanged)
#define RESC 32                // rescored per row

typedef short bf16x8 __attribute__((ext_vector_type(8)));
typedef float f32x4 __attribute__((ext_vector_type(4)));

__device__ __forceinline__ unsigned short f2b(float f) {
    unsigned int u = __float_as_uint(f);
    u += 0x7FFFu + ((u >> 16) & 1u);       // RNE to bf16
    return (unsigned short)(u >> 16);
}

// ascending (d, idx) top-K insert, fully static indices
template <int K>
__device__ __forceinline__ void push(float d, int gi, float (&bd)[K], int (&bi)[K]) {
    if (d > bd[K - 1] || (d == bd[K - 1] && gi >= bi[K - 1])) return;
    bd[K - 1] = d; bi[K - 1] = gi;
#pragma unroll
    for (int p = K - 1; p > 0; --p) {
        bool sw = (bd[p] < bd[p - 1]) || (bd[p] == bd[p - 1] && bi[p] < bi[p - 1]);
        if (sw) {
            float td = bd[p]; bd[p] = bd[p - 1]; bd[p - 1] = td;
            int   ti = bi[p]; bi[p] = bi[p - 1]; bi[p - 1] = ti;
        }
    }
}

// ascending top-K insert on packed uint32 keys ((dq<<16)|gi) — one compare/reject
template <int K>
__device__ __forceinline__ void pushk(unsigned int k, unsigned int (&lst)[K]) {
    if (k >= lst[K - 1]) return;
    lst[K - 1] = k;
#pragma unroll
    for (int p = K - 1; p > 0; --p) {
        if (lst[p] < lst[p - 1]) {
            unsigned int t = lst[p]; lst[p] = lst[p - 1]; lst[p - 1] = t;
        }
    }
}

// fp32 -> bf16 (RNE) bulk convert, 8 elems/thread
__global__ void cvt_bf16_kernel(const float* __restrict__ src,
                                unsigned short* __restrict__ dst, int n8) {
    int i = blockIdx.x * blockDim.x + threadIdx.x;
    if (i >= n8) return;
    const float4* s = (const float4*)src;
    float4 a0 = s[i * 2], a1 = s[i * 2 + 1];
    bf16x8 h;
    h[0] = (short)f2b(a0.x); h[1] = (short)f2b(a0.y);
    h[2] = (short)f2b(a0.z); h[3] = (short)f2b(a0.w);
    h[4] = (short)f2b(a1.x); h[5] = (short)f2b(a1.y);
    h[6] = (short)f2b(a1.z); h[7] = (short)f2b(a1.w);
    *(bf16x8*)(dst + (size_t)i * 8) = h;
}

// ||y||^2 per Y row, fp64 accumulate, one wave per row. (verified)
__global__ void ysq_kernel(const float* __restrict__ Y, float* __restrict__ ysq) {
    int row  = (blockIdx.x * blockDim.x + threadIdx.x) >> 6;
    int lane = threadIdx.x & 63;
    if (row >= NY) return;
    const float4* yr = reinterpret_cast<const float4*>(Y + (size_t)row * DIM);
    double s = 0.0;
#pragma unroll
    for (int i = 0; i < 2; ++i) {
        float4 v = yr[lane + 64 * i];
        s += (double)v.x * v.x + (double)v.y * v.y + (double)v.z * v.z + (double)v.w * v.w;
    }
#pragma unroll
    for (int off = 32; off > 0; off >>= 1) s += __shfl_xor(s, off, 64);
    if (lane == 0) ysq[row] = (float)s;
}

// Coarse: G = Y_tile . X^T via bf16 MFMA (global_load_lds, swizzled source);
// per-lane packed-key top-8 lists; two-pass LDS merge -> top-8 per (row,chunk).
__global__ __launch_bounds__(256, 4) void knn_coarse_fast(
        const unsigned short* __restrict__ Xb, const unsigned short* __restrict__ Yb,
        const float* __restrict__ ysq,
        unsigned int* __restrict__ cand_k, int ypass) {
    // [0,16K) As = Y tile [128 rows][128 B] (source-swizzled); [16K,32K) Bs = X;
    // [32K,32K+512) ysq_s. Merge reuses [0,16896).
    __shared__ __align__(16) char smem[33280];
    char* As = smem;
    char* Bs = smem + 16384;
    float* ysq_s = (float*)(smem + 32768);

    const int tid  = threadIdx.x;
    const int lane = tid & 63;
    const int w    = tid >> 6;
    const int chunk = blockIdx.x;            // 0..15
    const int row0  = blockIdx.y * BN;       // X rows of this block
    const int ybase = ypass * ROWS_PER_PASS + chunk * COLS_PER_CHUNK;
    const int m0 = (w >> 1) * 64;            // wave quadrant: Y side
    const int n0 = (w & 1) * 64;             //                X side
    const int l15 = lane & 15;
    const int lg  = lane >> 4;               // 0..3

    // staging geometry (verified round 5): lane covers 16 B
    const int srow = lane >> 3;                     // 0..7
    const int scb  = ((lane & 7) ^ srow) << 4;      // swizzled source chunk (bytes)
    const char* pX = (const char*)Xb + (size_t)(row0 + w * 32 + srow) * (DIM * 2) + scb;

    // kb_[nf][*]: packed-key top-8 for X row n0+nf*16+l15 over this lane's Y strata
    unsigned int kb_[4][LPT];
#pragma unroll
    for (int nf = 0; nf < 4; ++nf)
#pragma unroll
        for (int m = 0; m < LPT; ++m) kb_[nf][m] = 0xffffffffu;

    for (int t = 0; t < TILES_PER_CHUNK; ++t) {
        const int ytile0 = ybase + t * BM;
        const char* pY = (const char*)Yb + (size_t)(ytile0 + w * 32 + srow) * (DIM * 2) + scb;

        f32x4 acc[4][4];
#pragma unroll
        for (int i = 0; i < 4; ++i)
#pragma unroll
            for (int j = 0; j < 4; ++j)
                acc[i][j] = (f32x4){0.f, 0.f, 0.f, 0.f};

        for (int kc = 0; kc < DIM; kc += BK) {
            __syncthreads();   // prior frag/ysq_s reads done before restaging
            if (kc == 0 && tid < 128) ysq_s[tid] = ysq[ytile0 + tid];
#pragma unroll
            for (int q = 0; q < 4; ++q) {
                __builtin_amdgcn_global_load_lds(
                    (const __attribute__((address_space(1))) void*)(pY + q * 8 * (DIM * 2) + kc * 2),
                    (__attribute__((address_space(3))) void*)(As + w * 4096 + q * 1024),
                    16, 0, 0);
                __builtin_amdgcn_global_load_lds(
                    (const __attribute__((address_space(1))) void*)(pX + q * 8 * (DIM * 2) + kc * 2),
                    (__attribute__((address_space(3))) void*)(Bs + w * 4096 + q * 1024),
                    16, 0, 0);
            }
            __syncthreads();

#pragma unroll
            for (int kk = 0; kk < BK; kk += 32) {
                const int kb = (kk + lg * 8) * 2;   // byte offset of lane's k slot
                bf16x8 af[4], bf[4];
#pragma unroll
                for (int mf = 0; mf < 4; ++mf) {
                    const int rr = m0 + mf * 16 + l15;
                    af[mf] = *(const bf16x8*)(As + rr * 128 + (kb ^ ((rr & 7) << 4)));
                }
#pragma unroll
                for (int nf = 0; nf < 4; ++nf) {
                    const int cc = n0 + nf * 16 + l15;
                    bf[nf] = *(const bf16x8*)(Bs + cc * 128 + (kb ^ ((cc & 7) << 4)));
                }
                __builtin_amdgcn_s_setprio(1);
#pragma unroll
                for (int mf = 0; mf < 4; ++mf)
#pragma unroll
                    for (int nf = 0; nf < 4; ++nf)
                        acc[mf][nf] = __builtin_amdgcn_mfma_f32_16x16x32_bf16(
                            af[mf], bf[nf], acc[mf][nf], 0, 0, 0);
                __builtin_amdgcn_s_setprio(0);
            }
        }

        // pack distances into 32-bit keys: (trunc(d*32) << 16) | gi  (gi < 2^16)
#pragma unroll
        for (int mf = 0; mf < 4; ++mf) {
            const int gibase = ytile0 + m0 + mf * 16 + lg * 4;
            float yq32[4];
#pragma unroll
            for (int j = 0; j < 4; ++j)
                yq32[j] = ysq_s[m0 + mf * 16 + lg * 4 + j] * 32.f;
#pragma unroll
            for (int nf = 0; nf < 4; ++nf) {
#pragma unroll
                for (int j = 0; j < 4; ++j) {
                    float d32 = fmaf(acc[mf][nf][j], -64.f, yq32[j]);   // 32*(yq - 2*dot)
                    d32 = fminf(fmaxf(d32, 0.f), 65535.f);
                    const unsigned int key =
                        ((unsigned int)d32 << 16) | (unsigned int)(gibase + j);
                    pushk<LPT>(key, kb_[nf]);
                }
            }
        }
    }

    // two-pass merge (64 rows each) reusing As/Bs region: 64 x 66 dwords
    __syncthreads();
    unsigned int* mbuf = (unsigned int*)smem;
    const int slot = (w >> 1) * 4 + lg;      // 0..7
#pragma unroll
    for (int h = 0; h < 2; ++h) {
        if ((w & 1) == h) {
#pragma unroll
            for (int nf = 0; nf < 4; ++nf) {
                const int r = nf * 16 + l15;  // row within this half
#pragma unroll
                for (int e = 0; e < LPT; ++e)
                    mbuf[r * 66 + slot * 8 + e] = kb_[nf][e];
            }
        }
        __syncthreads();
        if (tid < 64) {
            unsigned int mk[KEEP];
#pragma unroll
            for (int m = 0; m < KEEP; ++m) mk[m] = 0xffffffffu;
            for (int s = 0; s < 8; ++s)
#pragma unroll
                for (int e = 0; e < LPT; ++e)
                    pushk<KEEP>(mbuf[tid * 66 + s * 8 + e], mk);
            const int row = row0 + h * 64 + tid;
            unsigned int* co = cand_k + (size_t)row * NCAND + (ypass * NCH + chunk) * KEEP;
#pragma unroll
            for (int m = 0; m < KEEP; ++m) co[m] = mk[m];
        }
        __syncthreads();
    }
}

// Rescore: coarse top-32 of 256 packed keys, then BIT-EXACT round-1 arithmetic.
__global__ __launch_bounds__(256) void knn_rescore(
        const float* __restrict__ X, const float* __restrict__ Y,
        const float* __restrict__ ysq,
        const unsigned int* __restrict__ cand_k,
        int* __restrict__ out) {
    __shared__ unsigned int ck[8][NCAND];
    __shared__ int   rci[8][RESC];
    __shared__ float rd[8][RESC];

    const int tid  = threadIdx.x;
    const int row0 = blockIdx.x * 8;

#pragma unroll
    for (int q = 0; q < 8; ++q) {
        const int idx = q * 256 + tid;       // 0..2047
        const int r = idx >> 8, j = idx & 255;
        ck[r][j] = cand_k[(size_t)(row0 + r) * NCAND + j];
    }
    __syncthreads();

    if (tid < 8) {
        unsigned int mk[RESC];
#pragma unroll
        for (int m = 0; m < RESC; ++m) mk[m] = 0xffffffffu;
        for (int j = 0; j < NCAND; ++j) pushk<RESC>(ck[tid][j], mk);
#pragma unroll
        for (int m = 0; m < RESC; ++m) rci[tid][m] = (int)(mk[m] & 0xffffu);
    }
    __syncthreads();

    {
        const int r = tid >> 5, c = tid & 31;
        const int row = row0 + r;
        const int yi = rci[r][c];
        const float* xr = X + (size_t)row * DIM;
        const float* yr = Y + (size_t)yi * DIM;
        double acc64 = 0.0;
        for (int kc = 0; kc < DIM; kc += 64) {
            float acc = 0.f;
#pragma unroll
            for (int k4 = 0; k4 < 16; ++k4) {
                float4 xv = *(const float4*)(xr + kc + k4 * 4);
                float4 yv = *(const float4*)(yr + kc + k4 * 4);
                acc = fmaf(xv.x, yv.x, acc);
                acc = fmaf(xv.y, yv.y, acc);
                acc = fmaf(xv.z, yv.z, acc);
                acc = fmaf(xv.w, yv.w, acc);
            }
            acc64 += (double)acc;
        }
        rd[r][c] = (float)((double)ysq[yi] - 2.0 * acc64);
    }
    __syncthreads();

    if (tid < 8) {
        float fd[KNN]; int fi[KNN];
#pragma unroll
        for (int m = 0; m < KNN; ++m) { fd[m] = INFINITY; fi[m] = 0x7fffffff; }
        for (int j = 0; j < RESC; ++j) push<KNN>(rd[tid][j], rci[tid][j], fd, fi);
        const int row = row0 + tid;
#pragma unroll
        for (int m = 0; m < KNN; ++m) out[row * KNN + m] = fi[m];
    }
}

extern "C" void kernel_launch(void* const* d_in, const int* in_sizes, int n_in,
                              void* d_out, int out_size, void* d_ws, size_t ws_size,
                              hipStream_t stream) {
    const float* X = (const float*)d_in[0];   // [8192, 512]
    const float* Y = (const float*)d_in[1];   // [65536, 512]
    int* out = (int*)d_out;                   // [8192, 8] int32

    char* ws = (char*)d_ws;
    float* ysq           = (float*)ws;                              // 256 KB
    unsigned int* cand_k = (unsigned int*)(ws + 262144);            // 8 MB
    size_t off = 262144 + (size_t)NX * NCAND * 4;                   // 8.25 MB
    unsigned short* Xbf = (unsigned short*)(ws + off);              // 8 MB
    unsigned short* Ybf = (unsigned short*)(ws + off + (size_t)NX * DIM * 2);  // 64 MB

    ysq_kernel<<<NY / 4, 256, 0, stream>>>(Y, ysq);
    cvt_bf16_kernel<<<(NX * DIM / 8) / 256, 256, 0, stream>>>(X, Xbf, NX * DIM / 8);
    cvt_bf16_kernel<<<(NY * DIM / 8) / 256, 256, 0, stream>>>(Y, Ybf, NY * DIM / 8);

    dim3 g1(NCH, NX / BN);   // 16 x 64 = 1024 blocks per pass, 4 per CU
    knn_coarse_fast<<<g1, 256, 0, stream>>>(Xbf, Ybf, ysq, cand_k, 0);
    knn_coarse_fast<<<g1, 256, 0, stream>>>(Xbf, Ybf, ysq, cand_k, 1);

    knn_rescore<<<NX / 8, 256, 0, stream>>>(X, Y, ysq, cand_k, out);
}

// Round 8
// 1149.462 us; speedup vs baseline: 2.1191x; 2.1191x over previous
//
#include <hip/hip_runtime.h>
#include <math.h>

#define NX 8192
#define NY 65536
#define DIM 512
#define KNN 8

#define BM 128                 // Y rows per streamed tile (MFMA M side)
#define BN 32                  // X rows resident in LDS per block (MFMA N side)
#define BK 64                  // K step
#define NCH 8                  // Y chunks per pass (grid.x); chunk <-> XCD
#define NPASS 4                // grid.z; chunk = 2 MB bf16 -> L2-resident
#define ROWS_PER_PASS (NY / NPASS)            // 16384
#define COLS_PER_CHUNK (ROWS_PER_PASS / NCH)  // 2048
#define TILES (COLS_PER_CHUNK / BM)           // 16
#define NSTEP (TILES * 8)                     // 128 K-steps per block
#define LPT 8                  // per-lane top-K (packed keys)
#define KEEP 8                 // kept per (row, chunk)
#define NCAND (NPASS * NCH * KEEP)            // 256 per row (rescore unchanged)
#define RESC 32                // rescored per row

typedef short bf16x8 __attribute__((ext_vector_type(8)));
typedef float f32x4 __attribute__((ext_vector_type(4)));

#define AS1(p) (const __attribute__((address_space(1))) void*)(p)
#define AS3(p) (__attribute__((address_space(3))) void*)(p)

__device__ __forceinline__ unsigned short f2b(float f) {
    unsigned int u = __float_as_uint(f);
    u += 0x7FFFu + ((u >> 16) & 1u);       // RNE to bf16
    return (unsigned short)(u >> 16);
}

template <int K>
__device__ __forceinline__ void push(float d, int gi, float (&bd)[K], int (&bi)[K]) {
    if (d > bd[K - 1] || (d == bd[K - 1] && gi >= bi[K - 1])) return;
    bd[K - 1] = d; bi[K - 1] = gi;
#pragma unroll
    for (int p = K - 1; p > 0; --p) {
        bool sw = (bd[p] < bd[p - 1]) || (bd[p] == bd[p - 1] && bi[p] < bi[p - 1]);
        if (sw) {
            float td = bd[p]; bd[p] = bd[p - 1]; bd[p - 1] = td;
            int   ti = bi[p]; bi[p] = bi[p - 1]; bi[p - 1] = ti;
        }
    }
}

template <int K>
__device__ __forceinline__ void pushk(unsigned int k, unsigned int (&lst)[K]) {
    if (k >= lst[K - 1]) return;
    lst[K - 1] = k;
#pragma unroll
    for (int p = K - 1; p > 0; --p) {
        if (lst[p] < lst[p - 1]) {
            unsigned int t = lst[p]; lst[p] = lst[p - 1]; lst[p - 1] = t;
        }
    }
}

__global__ void cvt_bf16_kernel(const float* __restrict__ src,
                                unsigned short* __restrict__ dst, int n8) {
    int i = blockIdx.x * blockDim.x + threadIdx.x;
    if (i >= n8) return;
    const float4* s = (const float4*)src;
    float4 a0 = s[i * 2], a1 = s[i * 2 + 1];
    bf16x8 h;
    h[0] = (short)f2b(a0.x); h[1] = (short)f2b(a0.y);
    h[2] = (short)f2b(a0.z); h[3] = (short)f2b(a0.w);
    h[4] = (short)f2b(a1.x); h[5] = (short)f2b(a1.y);
    h[6] = (short)f2b(a1.z); h[7] = (short)f2b(a1.w);
    *(bf16x8*)(dst + (size_t)i * 8) = h;
}

__global__ void ysq_kernel(const float* __restrict__ Y, float* __restrict__ ysq) {
    int row  = (blockIdx.x * blockDim.x + threadIdx.x) >> 6;
    int lane = threadIdx.x & 63;
    if (row >= NY) return;
    const float4* yr = reinterpret_cast<const float4*>(Y + (size_t)row * DIM);
    double s = 0.0;
#pragma unroll
    for (int i = 0; i < 2; ++i) {
        float4 v = yr[lane + 64 * i];
        s += (double)v.x * v.x + (double)v.y * v.y + (double)v.z * v.z + (double)v.w * v.w;
    }
#pragma unroll
    for (int off = 32; off > 0; off >>= 1) s += __shfl_xor(s, off, 64);
    if (lane == 0) ysq[row] = (float)s;
}

// Coarse: X tile (32 rows, full D) resident in LDS; Y streamed through a
// per-wave double-buffered As with counted vmcnt (no barriers in K loop).
__global__ __launch_bounds__(256, 2) void knn_coarse_fast(
        const unsigned short* __restrict__ Xb, const unsigned short* __restrict__ Yb,
        const float* __restrict__ ysq,
        unsigned int* __restrict__ cand_k) {
    // [0,32K) Xs [32 rows][1024 B], XOR-swizzled per 128-B segment.
    // [32K,64K) As dbuf: 2 x [128 rows][128 B], per-wave 4 KB slices.
    __shared__ __align__(16) char smem[65536];
    char* Xs = smem;
    char* As = smem + 32768;

    const int tid  = threadIdx.x;
    const int lane = tid & 63;
    const int w    = tid >> 6;
    const int l15  = lane & 15;
    const int lg   = lane >> 4;              // 0..3
    const int chunk = blockIdx.x;            // 0..7 (== XCD)
    const int row0  = blockIdx.y * BN;       // X rows of this block
    const int ypass = blockIdx.z;            // 0..3
    const int ybase = ypass * ROWS_PER_PASS + chunk * COLS_PER_CHUNK;

    // ---- stage X tile once: row r staged by one 1 KB wave-inst ----
    {
        const int xseg = lane >> 3;          // 128-B segment 0..7
        const int xc   = lane & 7;           // 16-B chunk in segment
#pragma unroll
        for (int i = 0; i < 8; ++i) {
            const int r = w * 8 + i;         // 0..31 ; r&7 == i
            const char* src = (const char*)Xb + ((size_t)(row0 + r) << 10)
                              + (xseg << 7) + ((xc ^ i) << 4);
            __builtin_amdgcn_global_load_lds(AS1(src), AS3(Xs + (r << 10)), 16, 0, 0);
        }
    }
    __syncthreads();   // drains vmcnt; Xs visible to all waves

    // ---- As staging (per-wave self-contained: rows w*32..w*32+31) ----
    const int srow = lane >> 3;                     // 0..7
    const int scb  = ((lane & 7) ^ srow) << 4;      // swizzled source chunk
    char* const myAs = As + (w << 12);
#define STAGE(t, kc, buf)                                                        \
    {                                                                            \
        const char* pY = (const char*)Yb                                         \
            + ((size_t)(ybase + (t) * BM + w * 32 + srow) << 10)                 \
            + ((kc) << 7) + scb;                                                 \
        char* dst = myAs + ((buf) << 14);                                        \
        _Pragma("unroll")                                                        \
        for (int q = 0; q < 4; ++q)                                              \
            __builtin_amdgcn_global_load_lds(AS1(pY + ((size_t)(q * 8) << 10)),  \
                                             AS3(dst + (q << 10)), 16, 0, 0);    \
    }

    unsigned int kb_[2][LPT];
#pragma unroll
    for (int nf = 0; nf < 2; ++nf)
#pragma unroll
        for (int m = 0; m < LPT; ++m) kb_[nf][m] = 0xffffffffu;

    STAGE(0, 0, 0);   // prologue

    for (int t = 0; t < TILES; ++t) {
        const int ytile0 = ybase + t * BM;

        // ysq for this tile, issued 7 K-steps ahead of use (volatile asm keeps
        // FIFO position between STAGE(t,0) and STAGE(t,1)).
        f32x4 yv0, yv1;
        const float* yp = ysq + ytile0 + w * 32 + lg * 4;
        asm volatile("global_load_dwordx4 %0, %1, off" : "=v"(yv0) : "v"(yp));
        asm volatile("global_load_dwordx4 %0, %1, off" : "=v"(yv1) : "v"(yp + 16));

        f32x4 acc[2][2];
#pragma unroll
        for (int i = 0; i < 2; ++i)
#pragma unroll
            for (int j = 0; j < 2; ++j) acc[i][j] = (f32x4){0.f, 0.f, 0.f, 0.f};

#pragma unroll
        for (int kc = 0; kc < 8; ++kc) {
            const int s = t * 8 + kc;
            const int cur = s & 1;
            if (s + 1 < NSTEP) {
                const int ns = s + 1;
                STAGE(ns >> 3, ns & 7, ns & 1);
                // wait for current buffer's 4 loads (oldest in FIFO).
                // kc==0: [st(t,0)4, ysq2, st(t,1)4] -> vmcnt(6); else vmcnt(4).
                if (kc == 0) asm volatile("s_waitcnt vmcnt(6)" ::: "memory");
                else         asm volatile("s_waitcnt vmcnt(4)" ::: "memory");
            } else {
                asm volatile("s_waitcnt vmcnt(0)" ::: "memory");
            }
            __builtin_amdgcn_sched_barrier(0);

            const char* Ab = myAs + (cur << 14);
#pragma unroll
            for (int kk = 0; kk < 2; ++kk) {
                const int kb = (kk * 32 + lg * 8) * 2;   // 0..127
                const int sw = kb ^ ((l15 & 7) << 4);
                bf16x8 af[2], bf[2];
                af[0] = *(const bf16x8*)(Ab + ((0  + l15) << 7) + sw);
                af[1] = *(const bf16x8*)(Ab + ((16 + l15) << 7) + sw);
                bf[0] = *(const bf16x8*)(Xs + ((size_t)(0  + l15) << 10) + (kc << 7) + sw);
                bf[1] = *(const bf16x8*)(Xs + ((size_t)(16 + l15) << 10) + (kc << 7) + sw);
#pragma unroll
                for (int mf = 0; mf < 2; ++mf)
#pragma unroll
                    for (int nf = 0; nf < 2; ++nf)
                        acc[mf][nf] = __builtin_amdgcn_mfma_f32_16x16x32_bf16(
                            af[mf], bf[nf], acc[mf][nf], 0, 0, 0);
            }
        }

        // epilogue: keys = (trunc(32*(ysq - 2*dot)) << 16) | yi   (yi < 2^16)
#pragma unroll
        for (int mf = 0; mf < 2; ++mf) {
            const int gib = ytile0 + w * 32 + mf * 16 + lg * 4;
            const f32x4 yv = mf ? yv1 : yv0;
#pragma unroll
            for (int nf = 0; nf < 2; ++nf) {
#pragma unroll
                for (int j = 0; j < 4; ++j) {
                    float d32 = fmaf(acc[mf][nf][j], -64.f, yv[j] * 32.f);
                    d32 = fminf(fmaxf(d32, 0.f), 65535.f);
                    pushk<LPT>(((unsigned int)d32 << 16) | (unsigned int)(gib + j),
                               kb_[nf]);
                }
            }
        }
    }
#undef STAGE

    // ---- merge 16 lane-lists per X row (reuses Xs region) ----
    __syncthreads();
    unsigned int* mbuf = (unsigned int*)smem;   // 32 rows x 130 dwords
    const int slot = w * 4 + lg;                // 0..15
#pragma unroll
    for (int nf = 0; nf < 2; ++nf) {
        const int r = nf * 16 + l15;
#pragma unroll
        for (int e = 0; e < LPT; ++e)
            mbuf[r * 130 + slot * 8 + e] = kb_[nf][e];
    }
    __syncthreads();
    if (tid < 32) {
        unsigned int mk[KEEP];
#pragma unroll
        for (int m = 0; m < KEEP; ++m) mk[m] = 0xffffffffu;
        for (int s2 = 0; s2 < 16; ++s2)
#pragma unroll
            for (int e = 0; e < LPT; ++e)
                pushk<KEEP>(mbuf[tid * 130 + s2 * 8 + e], mk);
        const int row = row0 + tid;
        unsigned int* co = cand_k + (size_t)row * NCAND + (ypass * NCH + chunk) * KEEP;
#pragma unroll
        for (int m = 0; m < KEEP; ++m) co[m] = mk[m];
    }
}

// Rescore: coarse top-32 of 256 packed keys, then BIT-EXACT round-1 arithmetic.
__global__ __launch_bounds__(256) void knn_rescore(
        const float* __restrict__ X, const float* __restrict__ Y,
        const float* __restrict__ ysq,
        const unsigned int* __restrict__ cand_k,
        int* __restrict__ out) {
    __shared__ unsigned int ck[8][NCAND];
    __shared__ int   rci[8][RESC];
    __shared__ float rd[8][RESC];

    const int tid  = threadIdx.x;
    const int row0 = blockIdx.x * 8;

#pragma unroll
    for (int q = 0; q < 8; ++q) {
        const int idx = q * 256 + tid;       // 0..2047
        const int r = idx >> 8, j = idx & 255;
        ck[r][j] = cand_k[(size_t)(row0 + r) * NCAND + j];
    }
    __syncthreads();

    if (tid < 8) {
        unsigned int mk[RESC];
#pragma unroll
        for (int m = 0; m < RESC; ++m) mk[m] = 0xffffffffu;
        for (int j = 0; j < NCAND; ++j) pushk<RESC>(ck[tid][j], mk);
#pragma unroll
        for (int m = 0; m < RESC; ++m) rci[tid][m] = (int)(mk[m] & 0xffffu);
    }
    __syncthreads();

    {
        const int r = tid >> 5, c = tid & 31;
        const int row = row0 + r;
        const int yi = rci[r][c];
        const float* xr = X + (size_t)row * DIM;
        const float* yr = Y + (size_t)yi * DIM;
        double acc64 = 0.0;
        for (int kc = 0; kc < DIM; kc += 64) {
            float acc = 0.f;
#pragma unroll
            for (int k4 = 0; k4 < 16; ++k4) {
                float4 xv = *(const float4*)(xr + kc + k4 * 4);
                float4 yv = *(const float4*)(yr + kc + k4 * 4);
                acc = fmaf(xv.x, yv.x, acc);
                acc = fmaf(xv.y, yv.y, acc);
                acc = fmaf(xv.z, yv.z, acc);
                acc = fmaf(xv.w, yv.w, acc);
            }
            acc64 += (double)acc;
        }
        rd[r][c] = (float)((double)ysq[yi] - 2.0 * acc64);
    }
    __syncthreads();

    if (tid < 8) {
        float fd[KNN]; int fi[KNN];
#pragma unroll
        for (int m = 0; m < KNN; ++m) { fd[m] = INFINITY; fi[m] = 0x7fffffff; }
        for (int j = 0; j < RESC; ++j) push<KNN>(rd[tid][j], rci[tid][j], fd, fi);
        const int row = row0 + tid;
#pragma unroll
        for (int m = 0; m < KNN; ++m) out[row * KNN + m] = fi[m];
    }
}

extern "C" void kernel_launch(void* const* d_in, const int* in_sizes, int n_in,
                              void* d_out, int out_size, void* d_ws, size_t ws_size,
                              hipStream_t stream) {
    const float* X = (const float*)d_in[0];   // [8192, 512]
    const float* Y = (const float*)d_in[1];   // [65536, 512]
    int* out = (int*)d_out;                   // [8192, 8] int32

    char* ws = (char*)d_ws;
    float* ysq           = (float*)ws;                              // 256 KB
    unsigned int* cand_k = (unsigned int*)(ws + 262144);            // 8 MB
    size_t off = 262144 + (size_t)NX * NCAND * 4;
    unsigned short* Xbf = (unsigned short*)(ws + off);              // 8 MB
    unsigned short* Ybf = (unsigned short*)(ws + off + (size_t)NX * DIM * 2);  // 64 MB

    ysq_kernel<<<NY / 4, 256, 0, stream>>>(Y, ysq);
    cvt_bf16_kernel<<<(NX * DIM / 8) / 256, 256, 0, stream>>>(X, Xbf, NX * DIM / 8);
    cvt_bf16_kernel<<<(NY * DIM / 8) / 256, 256, 0, stream>>>(Y, Ybf, NY * DIM / 8);

    dim3 g1(NCH, NX / BN, NPASS);   // 8 x 256 x 4 = 8192 blocks, chunk==XCD
    knn_coarse_fast<<<g1, 256, 0, stream>>>(Xbf, Ybf, ysq, cand_k);

    knn_rescore<<<NX / 8, 256, 0, stream>>>(X, Y, ysq, cand_k, out);
}

// Round 9
// 952.896 us; speedup vs baseline: 2.5562x; 1.2063x over previous
//
#include <hip/hip_runtime.h>
#include <math.h>

#define NX 8192
#define NY 65536
#define DIM 512
#define KNN 8

#define BM 128                 // Y rows per tile (MFMA M side)
#define BN 128                 // X rows per block (MFMA N side)
#define NCH 8                  // Y chunks per pass (grid.x); chunk == XCD
#define NPASS 4                // grid.z; Y chunk = 2 MB bf16 -> L2-resident
#define ROWS_PER_PASS (NY / NPASS)            // 16384
#define COLS_PER_CHUNK (ROWS_PER_PASS / NCH)  // 2048
#define TILES (COLS_PER_CHUNK / BM)           // 16
#define LPT 8                  // per-lane top-K (packed keys)
#define KEEP 8                 // kept per (row, chunk-slot)
#define NCAND (NPASS * NCH * KEEP)            // 256 per row (rescore unchanged)
#define RESC 32                // rescored per row

typedef short bf16x8 __attribute__((ext_vector_type(8)));
typedef float f32x4 __attribute__((ext_vector_type(4)));

#define AS1(p) (const __attribute__((address_space(1))) void*)(p)
#define AS3(p) (__attribute__((address_space(3))) void*)(p)

__device__ __forceinline__ unsigned short f2b(float f) {
    unsigned int u = __float_as_uint(f);
    u += 0x7FFFu + ((u >> 16) & 1u);       // RNE to bf16
    return (unsigned short)(u >> 16);
}

template <int K>
__device__ __forceinline__ void push(float d, int gi, float (&bd)[K], int (&bi)[K]) {
    if (d > bd[K - 1] || (d == bd[K - 1] && gi >= bi[K - 1])) return;
    bd[K - 1] = d; bi[K - 1] = gi;
#pragma unroll
    for (int p = K - 1; p > 0; --p) {
        bool sw = (bd[p] < bd[p - 1]) || (bd[p] == bd[p - 1] && bi[p] < bi[p - 1]);
        if (sw) {
            float td = bd[p]; bd[p] = bd[p - 1]; bd[p - 1] = td;
            int   ti = bi[p]; bi[p] = bi[p - 1]; bi[p - 1] = ti;
        }
    }
}

template <int K>
__device__ __forceinline__ void pushk(unsigned int k, unsigned int (&lst)[K]) {
    if (k >= lst[K - 1]) return;
    lst[K - 1] = k;
#pragma unroll
    for (int p = K - 1; p > 0; --p) {
        if (lst[p] < lst[p - 1]) {
            unsigned int t = lst[p]; lst[p] = lst[p - 1]; lst[p - 1] = t;
        }
    }
}

__global__ void cvt_bf16_kernel(const float* __restrict__ src,
                                unsigned short* __restrict__ dst, int n8) {
    int i = blockIdx.x * blockDim.x + threadIdx.x;
    if (i >= n8) return;
    const float4* s = (const float4*)src;
    float4 a0 = s[i * 2], a1 = s[i * 2 + 1];
    bf16x8 h;
    h[0] = (short)f2b(a0.x); h[1] = (short)f2b(a0.y);
    h[2] = (short)f2b(a0.z); h[3] = (short)f2b(a0.w);
    h[4] = (short)f2b(a1.x); h[5] = (short)f2b(a1.y);
    h[6] = (short)f2b(a1.z); h[7] = (short)f2b(a1.w);
    *(bf16x8*)(dst + (size_t)i * 8) = h;
}

__global__ void ysq_kernel(const float* __restrict__ Y, float* __restrict__ ysq) {
    int row  = (blockIdx.x * blockDim.x + threadIdx.x) >> 6;
    int lane = threadIdx.x & 63;
    if (row >= NY) return;
    const float4* yr = reinterpret_cast<const float4*>(Y + (size_t)row * DIM);
    double s = 0.0;
#pragma unroll
    for (int i = 0; i < 2; ++i) {
        float4 v = yr[lane + 64 * i];
        s += (double)v.x * v.x + (double)v.y * v.y + (double)v.z * v.z + (double)v.w * v.w;
    }
#pragma unroll
    for (int off = 32; off > 0; off >>= 1) s += __shfl_xor(s, off, 64);
    if (lane == 0) ysq[row] = (float)s;
}

// Coarse: 128x128 block tile (64x64 per wave, round-6 fragment geometry) with
// double-buffered As/Bs, raw s_barrier + counted vmcnt (loads in flight across
// barriers), L2-resident Y chunk per XCD.
__global__ __launch_bounds__(256, 2) void knn_coarse_fast(
        const unsigned short* __restrict__ Xb, const unsigned short* __restrict__ Yb,
        const float* __restrict__ ysq,
        unsigned int* __restrict__ cand_k) {
    // [0,32K) As dbuf = 2 x [128 rows][128 B] Y tiles (source-swizzled);
    // [32K,64K) Bs dbuf = X tiles. Merge reuses [0, 33.8K).
    __shared__ __align__(16) char smem[65536];
    char* As = smem;
    char* Bs = smem + 32768;

    const int tid  = threadIdx.x;
    const int lane = tid & 63;
    const int w    = tid >> 6;
    const int l15  = lane & 15;
    const int lg   = lane >> 4;              // 0..3
    const int chunk = blockIdx.x;            // 0..7 (== XCD)
    const int row0  = blockIdx.y * BN;       // X rows of this block
    const int ypass = blockIdx.z;            // 0..3
    const int ybase = ypass * ROWS_PER_PASS + chunk * COLS_PER_CHUNK;
    const int m0 = (w >> 1) * 64;            // wave quadrant: Y side
    const int n0 = (w & 1) * 64;             //                X side

    // staging geometry (proven r5-8): lane covers 16 B; 8 insts/wave/K-step
    const int srow = lane >> 3;                     // 0..7
    const int scb  = ((lane & 7) ^ srow) << 4;      // swizzled source chunk
    const char* pXbase = (const char*)Xb
        + ((size_t)(row0 + w * 32 + srow) << 10) + scb;

#define STAGE(tt, kcc, buf)                                                      \
    {                                                                            \
        const char* pY_ = (const char*)Yb                                        \
            + ((size_t)(ybase + (tt) * BM + w * 32 + srow) << 10)                \
            + ((kcc) << 7) + scb;                                                \
        const char* pX_ = pXbase + ((kcc) << 7);                                 \
        char* dA_ = As + ((buf) << 14) + (w << 12);                              \
        char* dB_ = Bs + ((buf) << 14) + (w << 12);                              \
        _Pragma("unroll")                                                        \
        for (int q = 0; q < 4; ++q) {                                            \
            __builtin_amdgcn_global_load_lds(AS1(pY_ + ((size_t)(q * 8) << 10)), \
                                             AS3(dA_ + (q << 10)), 16, 0, 0);    \
            __builtin_amdgcn_global_load_lds(AS1(pX_ + ((size_t)(q * 8) << 10)), \
                                             AS3(dB_ + (q << 10)), 16, 0, 0);    \
        }                                                                        \
    }

    unsigned int kb_[4][LPT];
#pragma unroll
    for (int nf = 0; nf < 4; ++nf)
#pragma unroll
        for (int m = 0; m < LPT; ++m) kb_[nf][m] = 0xffffffffu;

    STAGE(0, 0, 0);   // prologue: 8 loads in flight

    for (int t = 0; t < TILES; ++t) {
        const int ytile0 = ybase + t * BM;

        // ysq rows this lane needs in the epilogue (asm: stays in our FIFO count)
        f32x4 yv0, yv1, yv2, yv3;
        {
            const float* yp = ysq + ytile0 + m0 + lg * 4;
            asm volatile("global_load_dwordx4 %0, %1, off" : "=v"(yv0) : "v"(yp));
            asm volatile("global_load_dwordx4 %0, %1, off" : "=v"(yv1) : "v"(yp + 16));
            asm volatile("global_load_dwordx4 %0, %1, off" : "=v"(yv2) : "v"(yp + 32));
            asm volatile("global_load_dwordx4 %0, %1, off" : "=v"(yv3) : "v"(yp + 48));
        }

        f32x4 acc[4][4];
#pragma unroll
        for (int i = 0; i < 4; ++i)
#pragma unroll
            for (int j = 0; j < 4; ++j) acc[i][j] = (f32x4){0.f, 0.f, 0.f, 0.f};

#pragma unroll
        for (int kc = 0; kc < 8; ++kc) {
            const int buf = kc & 1;
            // stage next K-step into the other buffer
            if (kc < 7) {
                STAGE(t, kc + 1, buf ^ 1);
                if (kc == 0) asm volatile("s_waitcnt vmcnt(12)" ::: "memory");
                else         asm volatile("s_waitcnt vmcnt(8)"  ::: "memory");
            } else if (t + 1 < TILES) {
                STAGE(t + 1, 0, buf ^ 1);
                asm volatile("s_waitcnt vmcnt(8)" ::: "memory");
            } else {
                asm volatile("s_waitcnt vmcnt(0)" ::: "memory");
            }
            __builtin_amdgcn_sched_barrier(0);
            __builtin_amdgcn_s_barrier();       // raw: no vmcnt drain

            const char* Ab = As + (buf << 14);
            const char* Bb = Bs + (buf << 14);
#pragma unroll
            for (int kk = 0; kk < 2; ++kk) {
                const int kbyte = kk * 64 + lg * 16;
                const int sw = kbyte ^ ((l15 & 7) << 4);
                bf16x8 af[4], bf[4];
#pragma unroll
                for (int mf = 0; mf < 4; ++mf)
                    af[mf] = *(const bf16x8*)(Ab + ((m0 + mf * 16 + l15) << 7) + sw);
#pragma unroll
                for (int nf = 0; nf < 4; ++nf)
                    bf[nf] = *(const bf16x8*)(Bb + ((n0 + nf * 16 + l15) << 7) + sw);
                __builtin_amdgcn_s_setprio(1);
#pragma unroll
                for (int mf = 0; mf < 4; ++mf)
#pragma unroll
                    for (int nf = 0; nf < 4; ++nf)
                        acc[mf][nf] = __builtin_amdgcn_mfma_f32_16x16x32_bf16(
                            af[mf], bf[nf], acc[mf][nf], 0, 0, 0);
                __builtin_amdgcn_s_setprio(0);
            }
            __builtin_amdgcn_s_barrier();       // readers done before restage
        }

        // epilogue: keys = (trunc(32*(ysq - 2*dot)) << 16) | yi   (yi < 2^16)
#pragma unroll
        for (int mf = 0; mf < 4; ++mf) {
            const int gib = ytile0 + m0 + mf * 16 + lg * 4;
            const f32x4 yv = (mf == 0) ? yv0 : (mf == 1) ? yv1 : (mf == 2) ? yv2 : yv3;
#pragma unroll
            for (int nf = 0; nf < 4; ++nf) {
#pragma unroll
                for (int j = 0; j < 4; ++j) {
                    float d32 = fmaf(acc[mf][nf][j], -64.f, yv[j] * 32.f);
                    d32 = fminf(fmaxf(d32, 0.f), 65535.f);
                    pushk<LPT>(((unsigned int)d32 << 16) | (unsigned int)(gib + j),
                               kb_[nf]);
                }
            }
        }
    }
#undef STAGE

    // ---- merge 8 lane-lists per X row (reuses smem; r6-proven layout) ----
    __syncthreads();
    unsigned int* mbuf = (unsigned int*)smem;   // 128 rows x 66 dwords = 33 KB
    const int slot = (w >> 1) * 4 + lg;         // 0..7
#pragma unroll
    for (int nf = 0; nf < 4; ++nf) {
        const int r = n0 + nf * 16 + l15;
#pragma unroll
        for (int e = 0; e < LPT; ++e)
            mbuf[r * 66 + slot * 8 + e] = kb_[nf][e];
    }
    __syncthreads();
    if (tid < 128) {
        unsigned int mk[KEEP];
#pragma unroll
        for (int m = 0; m < KEEP; ++m) mk[m] = 0xffffffffu;
        for (int s2 = 0; s2 < 8; ++s2)
#pragma unroll
            for (int e = 0; e < LPT; ++e)
                pushk<KEEP>(mbuf[tid * 66 + s2 * 8 + e], mk);
        const int row = row0 + tid;
        unsigned int* co = cand_k + (size_t)row * NCAND + (ypass * NCH + chunk) * KEEP;
#pragma unroll
        for (int m = 0; m < KEEP; ++m) co[m] = mk[m];
    }
}

// Rescore: coarse top-32 of 256 packed keys, then BIT-EXACT round-1 arithmetic.
__global__ __launch_bounds__(256) void knn_rescore(
        const float* __restrict__ X, const float* __restrict__ Y,
        const float* __restrict__ ysq,
        const unsigned int* __restrict__ cand_k,
        int* __restrict__ out) {
    __shared__ unsigned int ck[8][NCAND];
    __shared__ int   rci[8][RESC];
    __shared__ float rd[8][RESC];

    const int tid  = threadIdx.x;
    const int row0 = blockIdx.x * 8;

#pragma unroll
    for (int q = 0; q < 8; ++q) {
        const int idx = q * 256 + tid;       // 0..2047
        const int r = idx >> 8, j = idx & 255;
        ck[r][j] = cand_k[(size_t)(row0 + r) * NCAND + j];
    }
    __syncthreads();

    if (tid < 8) {
        unsigned int mk[RESC];
#pragma unroll
        for (int m = 0; m < RESC; ++m) mk[m] = 0xffffffffu;
        for (int j = 0; j < NCAND; ++j) pushk<RESC>(ck[tid][j], mk);
#pragma unroll
        for (int m = 0; m < RESC; ++m) rci[tid][m] = (int)(mk[m] & 0xffffu);
    }
    __syncthreads();

    {
        const int r = tid >> 5, c = tid & 31;
        const int row = row0 + r;
        const int yi = rci[r][c];
        const float* xr = X + (size_t)row * DIM;
        const float* yr = Y + (size_t)yi * DIM;
        double acc64 = 0.0;
        for (int kc = 0; kc < DIM; kc += 64) {
            float acc = 0.f;
#pragma unroll
            for (int k4 = 0; k4 < 16; ++k4) {
                float4 xv = *(const float4*)(xr + kc + k4 * 4);
                float4 yv = *(const float4*)(yr + kc + k4 * 4);
                acc = fmaf(xv.x, yv.x, acc);
                acc = fmaf(xv.y, yv.y, acc);
                acc = fmaf(xv.z, yv.z, acc);
                acc = fmaf(xv.w, yv.w, acc);
            }
            acc64 += (double)acc;
        }
        rd[r][c] = (float)((double)ysq[yi] - 2.0 * acc64);
    }
    __syncthreads();

    if (tid < 8) {
        float fd[KNN]; int fi[KNN];
#pragma unroll
        for (int m = 0; m < KNN; ++m) { fd[m] = INFINITY; fi[m] = 0x7fffffff; }
        for (int j = 0; j < RESC; ++j) push<KNN>(rd[tid][j], rci[tid][j], fd, fi);
        const int row = row0 + tid;
#pragma unroll
        for (int m = 0; m < KNN; ++m) out[row * KNN + m] = fi[m];
    }
}

extern "C" void kernel_launch(void* const* d_in, const int* in_sizes, int n_in,
                              void* d_out, int out_size, void* d_ws, size_t ws_size,
                              hipStream_t stream) {
    const float* X = (const float*)d_in[0];   // [8192, 512]
    const float* Y = (const float*)d_in[1];   // [65536, 512]
    int* out = (int*)d_out;                   // [8192, 8] int32

    char* ws = (char*)d_ws;
    float* ysq           = (float*)ws;                              // 256 KB
    unsigned int* cand_k = (unsigned int*)(ws + 262144);            // 8 MB
    size_t off = 262144 + (size_t)NX * NCAND * 4;
    unsigned short* Xbf = (unsigned short*)(ws + off);              // 8 MB
    unsigned short* Ybf = (unsigned short*)(ws + off + (size_t)NX * DIM * 2);  // 64 MB

    ysq_kernel<<<NY / 4, 256, 0, stream>>>(Y, ysq);
    cvt_bf16_kernel<<<(NX * DIM / 8) / 256, 256, 0, stream>>>(X, Xbf, NX * DIM / 8);
    cvt_bf16_kernel<<<(NY * DIM / 8) / 256, 256, 0, stream>>>(Y, Ybf, NY * DIM / 8);

    dim3 g1(NCH, NX / BN, NPASS);   // 8 x 64 x 4 = 2048 blocks, chunk == XCD
    knn_coarse_fast<<<g1, 256, 0, stream>>>(Xbf, Ybf, ysq, cand_k);

    knn_rescore<<<NX / 8, 256, 0, stream>>>(X, Y, ysq, cand_k, out);
}